// Round 16
// baseline (87.497 us; speedup 1.0000x reference)
//
#include <hip/hip_runtime.h>

#define HH 224
#define WW 224
#define NXCD 8

typedef float vf2 __attribute__((ext_vector_type(2)));
typedef float vf3 __attribute__((ext_vector_type(3)));

// out[b,y,x,c] = sbp[b, Yi, Xi, c]
//   Yi = int((y + dy) mod H)  (jnp.remainder semantics), clamped to H-1
//   Xi = int((x + dx) mod W), clamped to W-1
//   sbp border = 0; interior = 0.25*(tl+tr+bl+br) of img (channels 0..2).
// Round-15 (44.8 us) + merged dwordx3 nt store + nt dx/dy load:
// VMEM instrs per 64 px: 8 -> 6 (test of the instruction-issue-rate model).
__global__ __launch_bounds__(256) void bilinear_gather_kernel(
    const float* __restrict__ x, float* __restrict__ out, int nwg) {
    // XCD-aware bijective swizzle (round 3->4: 2.2x).
    int p = blockIdx.x;
    int xcd = p % NXCD, idx = p / NXCD;
    int q = nwg / NXCD, r = nwg % NXCD;
    int lb = (xcd < r ? xcd * (q + 1) : r * (q + 1) + (xcd - r) * q) + idx;

    int i = lb * 256 + threadIdx.x;  // total = 6422528 = 25088*256, no guard

    int px = i % WW;
    int t  = i / WW;
    int py = t % HH;
    int b  = t / HH;

    // dx,dy: 8 B at pixel*20+12 (dword-aligned); never re-read -> nontemporal.
    vf2 d = __builtin_nontemporal_load((const vf2*)(x + (size_t)i * 5 + 3));
    float dx = d.x, dy = d.y;

    // Exact jnp.remainder for |d| < 224 (v in (-224,448)):
    //   [224,448): v-224 exact (Sterbenz). (-224,0): fmod(v)=v, remainder
    //   adds 224 -- same single fl(v+224) we compute (may round to exactly
    //   224.0 for tiny negatives -> clamped below, matching JAX OOB clamp).
    float rx = (float)px + dx;
    if (rx < 0.f) rx += (float)WW;
    else if (rx >= (float)WW) rx -= (float)WW;
    float ry = (float)py + dy;
    if (ry < 0.f) ry += (float)HH;
    else if (ry >= (float)HH) ry -= (float)HH;

    int xi = (int)rx; if (xi > WW - 1) xi = WW - 1;
    int yi = (int)ry; if (yi > HH - 1) yi = HH - 1;

    float r0 = 0.f, g0 = 0.f, b0 = 0.f;
    if (xi >= 1 && xi <= WW - 2 && yi >= 1 && yi <= HH - 2) {
        const float* base = x + (size_t)b * HH * WW * 5;
        const float* p00 = base + ((size_t)(yi - 1) * WW + (xi - 1)) * 5;
        const float* p01 = base + ((size_t)(yi - 1) * WW + (xi + 1)) * 5;
        const float* p10 = base + ((size_t)(yi + 1) * WW + (xi - 1)) * 5;
        const float* p11 = base + ((size_t)(yi + 1) * WW + (xi + 1)) * 5;
        r0 = 0.25f * (p00[0] + p01[0] + p10[0] + p11[0]);
        g0 = 0.25f * (p00[1] + p01[1] + p10[1] + p11[1]);
        b0 = 0.25f * (p00[2] + p01[2] + p10[2] + p11[2]);
    }
    // One dwordx3 nontemporal store (12 B, dword-aligned at i*12).
    vf3 v = {r0, g0, b0};
    __builtin_nontemporal_store(v, (vf3*)(out + (size_t)i * 3));
}

extern "C" void kernel_launch(void* const* d_in, const int* in_sizes, int n_in,
                              void* d_out, int out_size, void* d_ws, size_t ws_size,
                              hipStream_t stream) {
    const float* x = (const float*)d_in[0];
    float* out = (float*)d_out;
    int total = in_sizes[0] / 5;        // B*H*W = 6422528
    int blocks = total / 256;           // 25088
    bilinear_gather_kernel<<<blocks, 256, 0, stream>>>(x, out, blocks);
}

// Round 17
// 48.649 us; speedup vs baseline: 1.7986x; 1.7986x over previous
//
#include <hip/hip_runtime.h>

#define HH 224
#define WW 224
#define NXCD 8

typedef float vf2 __attribute__((ext_vector_type(2)));
typedef float vf3 __attribute__((ext_vector_type(3)));

// out[b,y,x,c] = sbp[b, Yi, Xi, c]
//   Yi = int((y + dy) mod H)  (jnp.remainder semantics), clamped to H-1
//   Xi = int((x + dx) mod W), clamped to W-1
//   sbp border = 0; interior = 0.25*(tl+tr+bl+br) of img (channels 0..2).
// Round-15 (44.8 us) + merged dwordx3 nt store. dx/dy load stays CACHED:
// round-16 lesson — nt on it evicts lines shared with neighboring RGB taps
// (interleaved layout), FETCH 63->88 MB, 2x regression.
__global__ __launch_bounds__(256) void bilinear_gather_kernel(
    const float* __restrict__ x, float* __restrict__ out, int nwg) {
    // XCD-aware bijective swizzle (round 3->4: 2.2x).
    int p = blockIdx.x;
    int xcd = p % NXCD, idx = p / NXCD;
    int q = nwg / NXCD, r = nwg % NXCD;
    int lb = (xcd < r ? xcd * (q + 1) : r * (q + 1) + (xcd - r) * q) + idx;

    int i = lb * 256 + threadIdx.x;  // total = 6422528 = 25088*256, no guard

    int px = i % WW;
    int t  = i / WW;
    int py = t % HH;
    int b  = t / HH;

    // dx,dy: one cached 8 B load (pixel*20+12, dword-aligned).
    vf2 d = *(const vf2*)(x + (size_t)i * 5 + 3);
    float dx = d.x, dy = d.y;

    // Exact jnp.remainder for |d| < 224 (v in (-224,448)):
    //   [224,448): v-224 exact (Sterbenz). (-224,0): fmod(v)=v, remainder
    //   adds 224 -- same single fl(v+224) we compute (may round to exactly
    //   224.0 for tiny negatives -> clamped below, matching JAX OOB clamp).
    float rx = (float)px + dx;
    if (rx < 0.f) rx += (float)WW;
    else if (rx >= (float)WW) rx -= (float)WW;
    float ry = (float)py + dy;
    if (ry < 0.f) ry += (float)HH;
    else if (ry >= (float)HH) ry -= (float)HH;

    int xi = (int)rx; if (xi > WW - 1) xi = WW - 1;
    int yi = (int)ry; if (yi > HH - 1) yi = HH - 1;

    float r0 = 0.f, g0 = 0.f, b0 = 0.f;
    if (xi >= 1 && xi <= WW - 2 && yi >= 1 && yi <= HH - 2) {
        const float* base = x + (size_t)b * HH * WW * 5;
        const float* p00 = base + ((size_t)(yi - 1) * WW + (xi - 1)) * 5;
        const float* p01 = base + ((size_t)(yi - 1) * WW + (xi + 1)) * 5;
        const float* p10 = base + ((size_t)(yi + 1) * WW + (xi - 1)) * 5;
        const float* p11 = base + ((size_t)(yi + 1) * WW + (xi + 1)) * 5;
        r0 = 0.25f * (p00[0] + p01[0] + p10[0] + p11[0]);
        g0 = 0.25f * (p00[1] + p01[1] + p10[1] + p11[1]);
        b0 = 0.25f * (p00[2] + p01[2] + p10[2] + p11[2]);
    }
    // One dwordx3 nontemporal store (12 B, dword-aligned at i*12); output is
    // write-once so nt is safe -- round 15 showed nt stores don't hurt FETCH.
    vf3 v = {r0, g0, b0};
    __builtin_nontemporal_store(v, (vf3*)(out + (size_t)i * 3));
}

extern "C" void kernel_launch(void* const* d_in, const int* in_sizes, int n_in,
                              void* d_out, int out_size, void* d_ws, size_t ws_size,
                              hipStream_t stream) {
    const float* x = (const float*)d_in[0];
    float* out = (float*)d_out;
    int total = in_sizes[0] / 5;        // B*H*W = 6422528
    int blocks = total / 256;           // 25088
    bilinear_gather_kernel<<<blocks, 256, 0, stream>>>(x, out, blocks);
}

// Round 18
// 44.981 us; speedup vs baseline: 1.9452x; 1.0815x over previous
//
#include <hip/hip_runtime.h>

#define HH 224
#define WW 224
#define NXCD 8

// out[b,y,x,c] = sbp[b, Yi, Xi, c]
//   Yi = int((y + dy) mod H)  (jnp.remainder semantics), clamped to H-1
//   Xi = int((x + dx) mod W), clamped to W-1
//   sbp border = 0; interior = 0.25*(tl+tr+bl+br) of img (channels 0..2).
// BEST CONFIG (round 15, 44.8 us): direct gather + XCD swizzle + cheap exact
// mod + 3 scalar nontemporal stores + CACHED dx/dy float2 load.
// Refuted alternatives: PPT=4 consecutive (84 us, line-span blowup); PPT=4
// wave-interleaved (48 us, neutral); LDS staging (46.6-78 us); nt dx/dy load
// (87 us, evicts shared gather lines); merged dwordx3 store (48.6 us).
__global__ __launch_bounds__(256) void bilinear_gather_kernel(
    const float* __restrict__ x, float* __restrict__ out, int nwg) {
    // XCD-aware bijective swizzle (round 3->4: 2.2x — gather-neighbor rows
    // share one per-XCD L2).
    int p = blockIdx.x;
    int xcd = p % NXCD, idx = p / NXCD;
    int q = nwg / NXCD, r = nwg % NXCD;
    int lb = (xcd < r ? xcd * (q + 1) : r * (q + 1) + (xcd - r) * q) + idx;

    int i = lb * 256 + threadIdx.x;  // total = 6422528 = 25088*256, no guard

    int px = i % WW;
    int t  = i / WW;
    int py = t % HH;
    int b  = t / HH;

    const float* pix = x + (size_t)i * 5;
    float2 d = *(const float2*)(pix + 3);  // cached: lines shared with taps
    float dx = d.x, dy = d.y;

    // Exact jnp.remainder for |d| < 224 (v in (-224,448)):
    //   [224,448): v-224 exact (Sterbenz). (-224,0): fmod(v)=v, remainder
    //   adds 224 -- same single fl(v+224) we compute (may round to exactly
    //   224.0 for tiny negatives -> clamped below, matching JAX OOB clamp).
    float rx = (float)px + dx;
    if (rx < 0.f) rx += (float)WW;
    else if (rx >= (float)WW) rx -= (float)WW;
    float ry = (float)py + dy;
    if (ry < 0.f) ry += (float)HH;
    else if (ry >= (float)HH) ry -= (float)HH;

    int xi = (int)rx; if (xi > WW - 1) xi = WW - 1;
    int yi = (int)ry; if (yi > HH - 1) yi = HH - 1;

    float r0 = 0.f, g0 = 0.f, b0 = 0.f;
    if (xi >= 1 && xi <= WW - 2 && yi >= 1 && yi <= HH - 2) {
        const float* base = x + (size_t)b * HH * WW * 5;
        const float* p00 = base + ((size_t)(yi - 1) * WW + (xi - 1)) * 5;
        const float* p01 = base + ((size_t)(yi - 1) * WW + (xi + 1)) * 5;
        const float* p10 = base + ((size_t)(yi + 1) * WW + (xi - 1)) * 5;
        const float* p11 = base + ((size_t)(yi + 1) * WW + (xi + 1)) * 5;
        r0 = 0.25f * (p00[0] + p01[0] + p10[0] + p11[0]);
        g0 = 0.25f * (p00[1] + p01[1] + p10[1] + p11[1]);
        b0 = 0.25f * (p00[2] + p01[2] + p10[2] + p11[2]);
    }
    // Non-temporal scalar stores: write-once output, never re-read.
    float* o = out + (size_t)i * 3;
    __builtin_nontemporal_store(r0, o);
    __builtin_nontemporal_store(g0, o + 1);
    __builtin_nontemporal_store(b0, o + 2);
}

extern "C" void kernel_launch(void* const* d_in, const int* in_sizes, int n_in,
                              void* d_out, int out_size, void* d_ws, size_t ws_size,
                              hipStream_t stream) {
    const float* x = (const float*)d_in[0];
    float* out = (float*)d_out;
    int total = in_sizes[0] / 5;        // B*H*W = 6422528
    int blocks = total / 256;           // 25088
    bilinear_gather_kernel<<<blocks, 256, 0, stream>>>(x, out, blocks);
}